// Round 6
// baseline (293.145 us; speedup 1.0000x reference)
//
#include <hip/hip_runtime.h>
#include <cfloat>

typedef unsigned short u16;
typedef unsigned int u32;
typedef __bf16 v8bf16 __attribute__((ext_vector_type(8)));
typedef float v4f32 __attribute__((ext_vector_type(4)));
typedef float v16f32 __attribute__((ext_vector_type(16)));

#define MPAD 4160            // 4097 keys padded to 65*64
// sqrt(1/8) * sqrt(log2(e)) : folds head-scale AND base-2 softmax into q and k
#define QKS 0.42466090f
#define NGRP 2048            // (16 bh) * (32 qt) * (4 waves)

__device__ __forceinline__ u16 f2bf(float f) {
  union { float f; u32 u; } v; v.f = f;
  u32 u = v.u;
  u32 r = (u + 0x7FFFu + ((u >> 16) & 1u)) >> 16;
  return (u16)r;
}

// pack two f32 -> one u32 holding (bf16(hi)<<16)|bf16(lo), truncating
__device__ __forceinline__ u32 pkbf(float lo, float hi) {
  union { float f; u32 u; } a, c;
  a.f = lo; c.f = hi;
  return __builtin_amdgcn_perm(c.u, a.u, 0x07060302);
}

__device__ __forceinline__ float asf(u32 u) {
  union { u32 u; float f; } v; v.u = u; return v.f;
}

// ---------------- prep: transpose fp32 [K][N] -> bf16 [N][K], with scale ----------
__global__ __launch_bounds__(256) void transpose_cast(const float* __restrict__ in,
    u16* __restrict__ out, int K, int N, float scale) {
  __shared__ float tile[32][33];
  int ntiles = N >> 5;
  int bx = blockIdx.x % ntiles, by = blockIdx.x / ntiles;
  int n0 = bx * 32, k0 = by * 32;
  int c = threadIdx.x & 31, r8 = threadIdx.x >> 5;
#pragma unroll
  for (int i = 0; i < 4; i++) {
    int r = r8 + i * 8;
    tile[r][c] = in[(size_t)(k0 + r) * N + n0 + c];
  }
  __syncthreads();
#pragma unroll
  for (int i = 0; i < 4; i++) {
    int r = r8 + i * 8;
    out[(size_t)(n0 + r) * K + k0 + c] = f2bf(tile[c][r] * scale);
  }
}

// ---------------- layernorm fp32 row(512) -> bf16 ----------------
__global__ __launch_bounds__(256) void ln_to_bf16(const float* __restrict__ in,
    const float* __restrict__ g, u16* __restrict__ out) {
  int lane = threadIdx.x & 63, w = threadIdx.x >> 6;
  int row = blockIdx.x * 4 + w;
  const float* p = in + (size_t)row * 512 + lane * 8;
  float4 f0 = *(const float4*)p;
  float4 f1 = *(const float4*)(p + 4);
  float v[8] = {f0.x, f0.y, f0.z, f0.w, f1.x, f1.y, f1.z, f1.w};
  float sum = 0.f, sq = 0.f;
#pragma unroll
  for (int i = 0; i < 8; i++) { sum += v[i]; sq += v[i] * v[i]; }
#pragma unroll
  for (int m = 1; m < 64; m <<= 1) { sum += __shfl_xor(sum, m); sq += __shfl_xor(sq, m); }
  float mean = sum * (1.f / 512.f);
  float var = sq * (1.f / 512.f) - mean * mean;
  float rstd = rsqrtf(var + 1e-5f);
  const float* gp = g + lane * 8;
  u16 o[8];
#pragma unroll
  for (int i = 0; i < 8; i++) o[i] = f2bf((v[i] - mean) * rstd * gp[i]);
  *(uint4*)&out[(size_t)row * 512 + lane * 8] = *(uint4*)o;
}

// ---------------- layernorm fp32 row(512) -> fp32 (final) ----------------
__global__ __launch_bounds__(256) void ln_to_f32(const float* __restrict__ in,
    const float* __restrict__ g, float* __restrict__ out) {
  int lane = threadIdx.x & 63, w = threadIdx.x >> 6;
  int row = blockIdx.x * 4 + w;
  const float* p = in + (size_t)row * 512 + lane * 8;
  float4 f0 = *(const float4*)p;
  float4 f1 = *(const float4*)(p + 4);
  float v[8] = {f0.x, f0.y, f0.z, f0.w, f1.x, f1.y, f1.z, f1.w};
  float sum = 0.f, sq = 0.f;
#pragma unroll
  for (int i = 0; i < 8; i++) { sum += v[i]; sq += v[i] * v[i]; }
#pragma unroll
  for (int m = 1; m < 64; m <<= 1) { sum += __shfl_xor(sum, m); sq += __shfl_xor(sq, m); }
  float mean = sum * (1.f / 512.f);
  float var = sq * (1.f / 512.f) - mean * mean;
  float rstd = rsqrtf(var + 1e-5f);
  const float* gp = g + lane * 8;
  float o[8];
#pragma unroll
  for (int i = 0; i < 8; i++) o[i] = (v[i] - mean) * rstd * gp[i];
  float* q = out + (size_t)row * 512 + lane * 8;
  *(float4*)q = make_float4(o[0], o[1], o[2], o[3]);
  *(float4*)(q + 4) = make_float4(o[4], o[5], o[6], o[7]);
}

// ---------------- cast fp32 -> bf16 ----------------
__global__ __launch_bounds__(256) void cast_f32_bf16(const float4* __restrict__ in,
    u16* __restrict__ out, int n4) {
  int i = blockIdx.x * 256 + threadIdx.x;
  if (i >= n4) return;
  float4 f = in[i];
  u16 o[4] = {f2bf(f.x), f2bf(f.y), f2bf(f.z), f2bf(f.w)};
  *(uint2*)&out[i * 4] = *(uint2*)o;
}

// ---------------- mask dtype detection + mask bias build ----------------
__global__ void detect_mask_dtype(const unsigned char* __restrict__ m, int* __restrict__ flag) {
  int i = blockIdx.x * 256 + threadIdx.x;  // scan first 8192 bytes
  if (i < 8192 && (i & 3) && m[i]) atomicOr(flag, 1);
}

// additive bias: 0 if attendable, -1e38 if masked/padding. index [b][MPAD]
__global__ void build_maskpad(const void* __restrict__ mask, const int* __restrict__ flag,
    float* __restrict__ mp) {
  int i = blockIdx.x * 256 + threadIdx.x;
  if (i >= 2 * MPAD) return;
  int b = i / MPAD, p = i - b * MPAD;
  float v;
  if (p == 0) v = 0.f;
  else if (p <= 4096) {
    int j = b * 4096 + (p - 1);
    int on = (*flag) ? (((const unsigned char*)mask)[j] != 0)
                     : (((const int*)mask)[j] != 0);
    v = on ? 0.f : -1e38f;
  } else v = -1e38f;
  mp[i] = v;
}

// ---------------- KVt: per (bh,kt) 8192-u16 tile: K-frags [0,4096) V-frags [4096,8192)
// K element (kl,d):  chunk = (((d>>4)*2 + ((d>>3)&1))*2 + (kl>>5))*32 + (kl&31), pos d&7
// V element (kl,d):  chunk = (((kl>>4)*2 + ((kl>>3)&1))*2 + (d>>5))*32 + (d&31), pos kl&7
__global__ __launch_bounds__(256) void fill_extras(const float* __restrict__ nullkv,
    u16* __restrict__ KVt) {
  int bh = blockIdx.x, tid = threadIdx.x;
  // zero tile kt=64 entirely (16 KB)
  size_t tb64 = ((size_t)bh * 65 + 64) * 8192;
  uint4 z = make_uint4(0, 0, 0, 0);
  for (int i = tid; i < 1024; i += 256)
    *(uint4*)&KVt[tb64 + (size_t)i * 8] = z;
  // null row kk=0 (tile 0, kl=0)
  size_t tb0 = (size_t)bh * 65 * 8192;
  if (tid < 64) {
    int d = tid;
    KVt[tb0 + (size_t)(d >> 3) * 512 + (d & 7)] = f2bf(nullkv[d] * QKS);
    KVt[tb0 + 4096 + (size_t)d * 8] = f2bf(nullkv[64 + d]);
  }
}

// ---------------- bf16 MFMA GEMM: C[M x N] = A[M x 512] * Bt[N x 512]^T -------------
// mode 0: out bf16 row-major [M][512]   (q projection, QKS folded in Bt)
// mode 1: scatter to KVt frag-layout (K scaled by QKS)
// mode 2: out fp32 row-major [M][512]
// staging via global_load_lds width=16 (no VGPR round-trip)
__global__ __launch_bounds__(256) void gemm_bf16(const u16* __restrict__ A,
    const u16* __restrict__ Bt, u16* __restrict__ outb, float* __restrict__ outf,
    u16* __restrict__ KVt, int Ncols, int mode) {
  __shared__ __attribute__((aligned(16))) u16 As[64 * 32];
  __shared__ __attribute__((aligned(16))) u16 Bs[64 * 32];
  int tiles_n = Ncols >> 6;
  int n0 = (blockIdx.x % tiles_n) * 64;
  int m0 = (blockIdx.x / tiles_n) * 64;
  int tid = threadIdx.x;
  int lane = tid & 63, w = tid >> 6, quad = lane >> 4, l15 = lane & 15;
  int arow = tid >> 2, acg = (tid & 3) * 8;
  v4f32 acc[4];
#pragma unroll
  for (int t = 0; t < 4; t++) acc[t] = (v4f32){0.f, 0.f, 0.f, 0.f};

  for (int k0 = 0; k0 < 512; k0 += 32) {
    __syncthreads();
    __builtin_amdgcn_global_load_lds((const u32*)&A[(size_t)(m0 + arow) * 512 + k0 + acg],
                                     (u32*)&As[tid * 8], 16, 0, 0);
    __builtin_amdgcn_global_load_lds((const u32*)&Bt[(size_t)(n0 + arow) * 512 + k0 + acg],
                                     (u32*)&Bs[tid * 8], 16, 0, 0);
    __syncthreads();
    v8bf16 af = *(const v8bf16*)&As[(w * 16 + l15) * 32 + quad * 8];
#pragma unroll
    for (int t = 0; t < 4; t++) {
      v8bf16 bf = *(const v8bf16*)&Bs[(t * 16 + l15) * 32 + quad * 8];
      acc[t] = __builtin_amdgcn_mfma_f32_16x16x32_bf16(af, bf, acc[t], 0, 0, 0);
    }
  }
  int rbase = m0 + w * 16 + quad * 4;
#pragma unroll
  for (int t = 0; t < 4; t++) {
    int col = n0 + t * 16 + l15;
#pragma unroll
    for (int r = 0; r < 4; r++) {
      float v = acc[t][r];
      int row = rbase + r;
      if (mode == 0) {
        outb[(size_t)row * 512 + col] = f2bf(v);
      } else if (mode == 2) {
        outf[(size_t)row * 512 + col] = v;
      } else {
        int b2 = row >> 12, mr = row & 4095;
        int kk = mr + 1, kt = kk >> 6, kl = kk & 63;
        int kvsel = col >> 9, hh = (col >> 6) & 7, d = col & 63;
        size_t tb = ((size_t)(b2 * 8 + hh) * 65 + kt) * 8192;
        if (kvsel == 0) {
          int chunk = (((d >> 4) * 2 + ((d >> 3) & 1)) * 2 + (kl >> 5)) * 32 + (kl & 31);
          KVt[tb + (size_t)chunk * 8 + (d & 7)] = f2bf(v * QKS);
        } else {
          int chunk = (((kl >> 4) * 2 + ((kl >> 3) & 1)) * 2 + (d >> 5)) * 32 + (d & 31);
          KVt[tb + 4096 + (size_t)chunk * 8 + (kl & 7)] = f2bf(v);
        }
      }
    }
  }
}

// ---------------- flash attention v6: split-K, double-buffered LDS, reg-bias -------
// grid: 1024 blocks of 256 thr (4 waves share one staged KV tile).
// bid>>5 = bh*2 + s_p, bid&31 = qt (128 q rows / block, 32 per wave).
// Single barrier per iteration; tile kt+1 prefetched into buf^1 right after
// the barrier so the next barrier's vmcnt(0) drain finds loads complete.
// Mask bias prefetched one iteration ahead into registers (C-initializer).
__global__ __launch_bounds__(256, 4) void attn_kernel(const u16* __restrict__ q,
    const u16* __restrict__ KVt, const float* __restrict__ maskbias,
    u32* __restrict__ Opart, float* __restrict__ lbuf) {
  __shared__ __attribute__((aligned(16))) u16 lds[2][8192];
  int bid = blockIdx.x;
  int qt = bid & 31, bhs = bid >> 5;
  int s_p = bhs & 1, bh = bhs >> 1;
  int b = bh >> 3, hh = bh & 7;
  int tid = threadIdx.x, lane = tid & 63, w = tid >> 6;
  int m31 = lane & 31, h = (lane >> 5) & 1;
  int grp = (bh * 32 + qt) * 4 + w;

  // Q B-frags: lane col = q0 + m31, k = ks*16 + h*8 (+0..7)
  int q0 = qt * 128 + w * 32;
  const u16* qp = q + (size_t)(b * 4096 + q0 + m31) * 512 + hh * 64 + h * 8;
  v8bf16 qf[4];
#pragma unroll
  for (int ks = 0; ks < 4; ks++) qf[ks] = *(const v8bf16*)&qp[ks * 16];

  v16f32 acc[2];
#pragma unroll
  for (int db = 0; db < 2; db++)
#pragma unroll
    for (int i = 0; i < 16; i++) acc[db][i] = 0.f;
  float l_st = 0.f;

  const u16* kvg = KVt + (size_t)bh * 65 * 8192;
  const float* mg = maskbias + b * MPAD;
  int kt0 = s_p * 33, ktn = 33 - s_p;   // s=0: tiles 0..32, s=1: 33..64

  // prologue: stage tile kt0 into buf 0, preload its bias into regs
  {
    const u16* gsrc = kvg + (size_t)kt0 * 8192 + (size_t)w * 512 + lane * 8;
#pragma unroll
    for (int i = 0; i < 4; i++)
      __builtin_amdgcn_global_load_lds((const u32*)(gsrc + (size_t)i * 2048),
                                       (u32*)&lds[0][(i * 4 + w) * 512], 16, 0, 0);
  }
  float4 bias_r[2][4];
#pragma unroll
  for (int kc = 0; kc < 2; kc++)
#pragma unroll
    for (int gg = 0; gg < 4; gg++)
      bias_r[kc][gg] = *(const float4*)&mg[kt0 * 64 + kc * 32 + gg * 8 + h * 4];

  for (int it = 0; it < ktn; ++it) {
    int kt = kt0 + it;
    int p = it & 1;
    __syncthreads();   // drains vmcnt: buf p ready; buf p^1 free to overwrite

    // prefetch next tile into the other buffer (completes during this compute)
    if (it + 1 < ktn) {
      const u16* gsrc = kvg + (size_t)(kt + 1) * 8192 + (size_t)w * 512 + lane * 8;
#pragma unroll
      for (int i = 0; i < 4; i++)
        __builtin_amdgcn_global_load_lds((const u32*)(gsrc + (size_t)i * 2048),
                                         (u32*)&lds[p ^ 1][(i * 4 + w) * 512], 16, 0, 0);
    }

    // S^T = K * Q^T with register bias as accumulator INIT
    // C layout: col q = m31, row key_local = (reg&3) + 8*(reg>>2) + 4h (+32*kc)
    v16f32 s[2];
#pragma unroll
    for (int kc = 0; kc < 2; kc++) {
#pragma unroll
      for (int gg = 0; gg < 4; gg++) {
        s[kc][gg * 4 + 0] = bias_r[kc][gg].x;
        s[kc][gg * 4 + 1] = bias_r[kc][gg].y;
        s[kc][gg * 4 + 2] = bias_r[kc][gg].z;
        s[kc][gg * 4 + 3] = bias_r[kc][gg].w;
      }
#pragma unroll
      for (int ks = 0; ks < 4; ks++) {
        v8bf16 kf = *(const v8bf16*)&lds[p][(((ks * 2 + h) * 2 + kc) * 32 + m31) * 8];
        s[kc] = __builtin_amdgcn_mfma_f32_32x32x16_bf16(kf, qf[ks], s[kc], 0, 0, 0);
      }
    }

    // prefetch next iteration's bias into regs (wait folds into next barrier)
    if (it + 1 < ktn) {
#pragma unroll
      for (int kc = 0; kc < 2; kc++)
#pragma unroll
        for (int gg = 0; gg < 4; gg++)
          bias_r[kc][gg] = *(const float4*)&mg[(kt + 1) * 64 + kc * 32 + gg * 8 + h * 4];
    }

    // p = exp2(s) directly (raw v_exp_f32; masked s ~ -1e38 -> 0)
    float rsum = 0.f;
#pragma unroll
    for (int kc = 0; kc < 2; kc++)
#pragma unroll
      for (int i = 0; i < 16; i++) {
        float pv = __builtin_amdgcn_exp2f(s[kc][i]);
        s[kc][i] = pv;
        rsum += pv;
      }
    rsum += __shfl_xor(rsum, 32);
    l_st += rsum;

    // P C-layout -> B-frags entirely in registers (cross-half shfl exchange)
    // B-frag jb=kc*2+s16 needs keys jb*16 + h*8 + {0..7}
    v8bf16 pf[4];
#pragma unroll
    for (int kc = 0; kc < 2; kc++)
#pragma unroll
      for (int s16 = 0; s16 < 2; s16++) {
        float lo[4], hi[4], rcv[4];
#pragma unroll
        for (int j = 0; j < 4; j++) {
          lo[j] = s[kc][s16 * 8 + j];         // own keys s16*16 + 4h + j
          hi[j] = s[kc][s16 * 8 + 4 + j];     // own keys s16*16 + 8 + 4h + j
          float snd = h ? lo[j] : hi[j];
          rcv[j] = __shfl_xor(snd, 32);
        }
        u32 pk[4];
        pk[0] = pkbf(h ? rcv[0] : lo[0], h ? rcv[1] : lo[1]);
        pk[1] = pkbf(h ? rcv[2] : lo[2], h ? rcv[3] : lo[3]);
        pk[2] = pkbf(h ? hi[0] : rcv[0], h ? hi[1] : rcv[1]);
        pk[3] = pkbf(h ? hi[2] : rcv[2], h ? hi[3] : rcv[3]);
        union { u32 u[4]; v8bf16 v; } pu;
        pu.u[0] = pk[0]; pu.u[1] = pk[1]; pu.u[2] = pk[2]; pu.u[3] = pk[3];
        pf[kc * 2 + s16] = pu.v;
      }

    // O^T += V^T * P^T : A = V-frags (lane row d = db*32+m31)
#pragma unroll
    for (int jb = 0; jb < 4; jb++)
#pragma unroll
      for (int db = 0; db < 2; db++) {
        v8bf16 vf = *(const v8bf16*)&lds[p][4096 + (((jb * 2 + h) * 2 + db) * 32 + m31) * 8];
        acc[db] = __builtin_amdgcn_mfma_f32_32x32x16_bf16(vf, pf[jb], acc[db], 0, 0, 0);
      }
  }

  // epilogue: dump raw accumulator (bf16-packed) + l
  size_t ob = (size_t)(s_p * NGRP + grp) * 16 * 64;
#pragma unroll
  for (int db = 0; db < 2; db++)
#pragma unroll
    for (int rp = 0; rp < 8; rp++)
      Opart[ob + (size_t)(db * 8 + rp) * 64 + lane] = pkbf(acc[db][2 * rp], acc[db][2 * rp + 1]);
  if (h == 0)
    lbuf[(size_t)(s_p * NGRP + grp) * 32 + m31] = l_st;
}

// ---------------- combine partials -> attnO (bf16 [row][512]) ----------------
__global__ __launch_bounds__(256) void attn_combine(const u32* __restrict__ Opart,
    const float* __restrict__ lbuf, u16* __restrict__ attnO) {
  __shared__ __attribute__((aligned(16))) u16 tl[4][2176];
  int tid = threadIdx.x, lane = tid & 63, w4 = tid >> 6;
  int m31 = lane & 31, h = (lane >> 5) & 1;
  int grp = blockIdx.x * 4 + w4;
  int wv = grp & 3, qt = (grp >> 2) & 31, bh = grp >> 7;
  int b = bh >> 3, hh = bh & 7;

  float l0 = lbuf[(size_t)grp * 32 + m31];
  float l1 = lbuf[(size_t)(NGRP + grp) * 32 + m31];
  float inv = 1.f / (l0 + l1);

#pragma unroll
  for (int db = 0; db < 2; db++)
#pragma unroll
    for (int rp = 0; rp < 8; rp++) {
      u32 a = Opart[((size_t)grp * 16 + db * 8 + rp) * 64 + lane];
      u32 c = Opart[((size_t)(NGRP + grp) * 16 + db * 8 + rp) * 64 + lane];
      float fe = (asf(a << 16) + asf(c << 16)) * inv;
      float fo = (asf(a & 0xFFFF0000u) + asf(c & 0xFFFF0000u)) * inv;
      int reg = 2 * rp;
      int d0 = (reg & 3) + 8 * (reg >> 2) + 4 * h + 32 * db;
      *(u32*)&tl[w4][m31 * 68 + d0] = pkbf(fe, fo);
    }
  __builtin_amdgcn_s_waitcnt(0);  // wave-private LDS round-trip
  int q0 = qt * 128 + wv * 32;
#pragma unroll
  for (int t2 = 0; t2 < 4; t2++) {
    int row = t2 * 8 + (lane >> 3), ch = lane & 7;
    uint4 val = *(uint4*)&tl[w4][row * 68 + ch * 8];
    *(uint4*)&attnO[(size_t)(b * 4096 + q0 + row) * 512 + hh * 64 + ch * 8] = val;
  }
}

// =======================================================================
extern "C" void kernel_launch(void* const* d_in, const int* in_sizes, int n_in,
                              void* d_out, int out_size, void* d_ws, size_t ws_size,
                              hipStream_t stream) {
  const float* x       = (const float*)d_in[0];
  const float* context = (const float*)d_in[1];
  const void*  mask    = d_in[2];
  const float* g_x     = (const float*)d_in[3];
  const float* null_kv = (const float*)d_in[4];
  const float* Wq      = (const float*)d_in[5];
  const float* Wkv     = (const float*)d_in[6];
  const float* Wo      = (const float*)d_in[7];
  const float* g_out   = (const float*)d_in[8];

  char* w = (char*)d_ws;
  size_t off = 0;
  auto alloc = [&](size_t bytes) { size_t o = off; off = (off + bytes + 255) & ~(size_t)255; return o; };

  u16* WqT    = (u16*)(w + alloc((size_t)512 * 512 * 2));
  u16* WkvT   = (u16*)(w + alloc((size_t)1024 * 512 * 2));
  u16* WoT    = (u16*)(w + alloc((size_t)512 * 512 * 2));
  float* mp   = (float*)(w + alloc((size_t)2 * MPAD * 4));
  int* flag   = (int*)(w + alloc(256));
  u16* KVt    = (u16*)(w + alloc((size_t)16 * 65 * 8192 * 2));
  u16* qb     = (u16*)(w + alloc((size_t)8192 * 512 * 2));
  u16* aO     = (u16*)(w + alloc((size_t)8192 * 512 * 2));
  size_t xn_off = alloc((size_t)8192 * 512 * 2);
  size_t cb_off = alloc((size_t)8192 * 512 * 2);
  float* lbb  = (float*)(w + alloc((size_t)2 * NGRP * 32 * 4));
  u16* xn   = (u16*)(w + xn_off);
  u16* cb   = (u16*)(w + cb_off);
  // Opart (2*2048*16*64 u32 = 16 MB) aliases xn+cb exactly (dead after proj GEMMs)
  u32* Opart = (u32*)(w + xn_off);
  float* OP  = (float*)(w + xn_off);  // fp32 16 MB, used after combine (Opart dead)

  hipMemsetAsync(flag, 0, 4, stream);
  detect_mask_dtype<<<32, 256, 0, stream>>>((const unsigned char*)mask, flag);
  build_maskpad<<<(2 * MPAD + 255) / 256, 256, 0, stream>>>(mask, flag, mp);

  transpose_cast<<<256, 256, 0, stream>>>(Wq, WqT, 512, 512, QKS);
  transpose_cast<<<512, 256, 0, stream>>>(Wkv, WkvT, 512, 1024, 1.0f);
  transpose_cast<<<256, 256, 0, stream>>>(Wo, WoT, 512, 512, 1.0f);

  ln_to_bf16<<<2048, 256, 0, stream>>>(x, g_x, xn);
  cast_f32_bf16<<<4096, 256, 0, stream>>>((const float4*)context, cb, 8192 * 512 / 4);
  fill_extras<<<16, 256, 0, stream>>>(null_kv, KVt);

  // q = ln(x) @ Wq * QKS   -> bf16 [8192][512]
  gemm_bf16<<<(8192 / 64) * (512 / 64), 256, 0, stream>>>(xn, WqT, qb, nullptr, nullptr, 512, 0);
  // kv = ctx @ Wkv -> scatter into KVt frag-layout (K x QKS)
  gemm_bf16<<<(8192 / 64) * (1024 / 64), 256, 0, stream>>>(cb, WkvT, nullptr, nullptr, KVt, 1024, 1);

  // split-K flash attention + combine
  attn_kernel<<<1024, 256, 0, stream>>>(qb, KVt, mp, Opart, lbb);
  attn_combine<<<NGRP / 4, 256, 0, stream>>>(Opart, lbb, aO);

  // out = attnO @ Wo -> fp32
  gemm_bf16<<<(8192 / 64) * (512 / 64), 256, 0, stream>>>(aO, WoT, nullptr, OP, nullptr, 512, 2);
  ln_to_f32<<<2048, 256, 0, stream>>>(OP, g_out, (float*)d_out);
}

// Round 7
// 289.496 us; speedup vs baseline: 1.0126x; 1.0126x over previous
//
#include <hip/hip_runtime.h>
#include <cfloat>

typedef unsigned short u16;
typedef unsigned int u32;
typedef __bf16 v8bf16 __attribute__((ext_vector_type(8)));
typedef float v4f32 __attribute__((ext_vector_type(4)));
typedef float v16f32 __attribute__((ext_vector_type(16)));

#define MPAD 4160            // 4097 keys padded to 65*64
// sqrt(1/8) * sqrt(log2(e)) : folds head-scale AND base-2 softmax into q and k
#define QKS 0.42466090f
#define NGRP 2048            // (16 bh) * (32 qt) * (4 waves)
#define NSPLIT 4

__device__ __forceinline__ u16 f2bf(float f) {
  union { float f; u32 u; } v; v.f = f;
  u32 u = v.u;
  u32 r = (u + 0x7FFFu + ((u >> 16) & 1u)) >> 16;
  return (u16)r;
}

// pack two f32 -> one u32 holding (bf16(hi)<<16)|bf16(lo), truncating
__device__ __forceinline__ u32 pkbf(float lo, float hi) {
  union { float f; u32 u; } a, c;
  a.f = lo; c.f = hi;
  return __builtin_amdgcn_perm(c.u, a.u, 0x07060302);
}

__device__ __forceinline__ float asf(u32 u) {
  union { u32 u; float f; } v; v.u = u; return v.f;
}

// ---------------- prep: fused transpose of Wq/Wkv/Wo fp32 [K][N] -> bf16 [N][K] ----
__global__ __launch_bounds__(256) void transpose_cast3(const float* __restrict__ Wq,
    const float* __restrict__ Wkv, const float* __restrict__ Wo,
    u16* __restrict__ WqT, u16* __restrict__ WkvT, u16* __restrict__ WoT) {
  __shared__ float tile[32][33];
  int bb = blockIdx.x;
  const float* in; u16* out; int N; float scale; int base;
  if (bb < 256)      { in = Wq;  out = WqT;  N = 512;  scale = QKS; base = bb; }
  else if (bb < 768) { in = Wkv; out = WkvT; N = 1024; scale = 1.f; base = bb - 256; }
  else               { in = Wo;  out = WoT;  N = 512;  scale = 1.f; base = bb - 768; }
  const int K = 512;
  int ntiles = N >> 5;
  int bx = base % ntiles, by = base / ntiles;
  int n0 = bx * 32, k0 = by * 32;
  int c = threadIdx.x & 31, r8 = threadIdx.x >> 5;
#pragma unroll
  for (int i = 0; i < 4; i++) {
    int r = r8 + i * 8;
    tile[r][c] = in[(size_t)(k0 + r) * N + n0 + c];
  }
  __syncthreads();
#pragma unroll
  for (int i = 0; i < 4; i++) {
    int r = r8 + i * 8;
    out[(size_t)(n0 + r) * K + k0 + c] = f2bf(tile[c][r] * scale);
  }
}

// ---------------- layernorm fp32 row(512) -> bf16 ----------------
__global__ __launch_bounds__(256) void ln_to_bf16(const float* __restrict__ in,
    const float* __restrict__ g, u16* __restrict__ out) {
  int lane = threadIdx.x & 63, w = threadIdx.x >> 6;
  int row = blockIdx.x * 4 + w;
  const float* p = in + (size_t)row * 512 + lane * 8;
  float4 f0 = *(const float4*)p;
  float4 f1 = *(const float4*)(p + 4);
  float v[8] = {f0.x, f0.y, f0.z, f0.w, f1.x, f1.y, f1.z, f1.w};
  float sum = 0.f, sq = 0.f;
#pragma unroll
  for (int i = 0; i < 8; i++) { sum += v[i]; sq += v[i] * v[i]; }
#pragma unroll
  for (int m = 1; m < 64; m <<= 1) { sum += __shfl_xor(sum, m); sq += __shfl_xor(sq, m); }
  float mean = sum * (1.f / 512.f);
  float var = sq * (1.f / 512.f) - mean * mean;
  float rstd = rsqrtf(var + 1e-5f);
  const float* gp = g + lane * 8;
  u16 o[8];
#pragma unroll
  for (int i = 0; i < 8; i++) o[i] = f2bf((v[i] - mean) * rstd * gp[i]);
  *(uint4*)&out[(size_t)row * 512 + lane * 8] = *(uint4*)o;
}

// ---------------- layernorm fp32 row(512) -> fp32 (final) ----------------
__global__ __launch_bounds__(256) void ln_to_f32(const float* __restrict__ in,
    const float* __restrict__ g, float* __restrict__ out) {
  int lane = threadIdx.x & 63, w = threadIdx.x >> 6;
  int row = blockIdx.x * 4 + w;
  const float* p = in + (size_t)row * 512 + lane * 8;
  float4 f0 = *(const float4*)p;
  float4 f1 = *(const float4*)(p + 4);
  float v[8] = {f0.x, f0.y, f0.z, f0.w, f1.x, f1.y, f1.z, f1.w};
  float sum = 0.f, sq = 0.f;
#pragma unroll
  for (int i = 0; i < 8; i++) { sum += v[i]; sq += v[i] * v[i]; }
#pragma unroll
  for (int m = 1; m < 64; m <<= 1) { sum += __shfl_xor(sum, m); sq += __shfl_xor(sq, m); }
  float mean = sum * (1.f / 512.f);
  float var = sq * (1.f / 512.f) - mean * mean;
  float rstd = rsqrtf(var + 1e-5f);
  const float* gp = g + lane * 8;
  float o[8];
#pragma unroll
  for (int i = 0; i < 8; i++) o[i] = (v[i] - mean) * rstd * gp[i];
  float* q = out + (size_t)row * 512 + lane * 8;
  *(float4*)q = make_float4(o[0], o[1], o[2], o[3]);
  *(float4*)(q + 4) = make_float4(o[4], o[5], o[6], o[7]);
}

// ---------------- cast fp32 -> bf16 ----------------
__global__ __launch_bounds__(256) void cast_f32_bf16(const float4* __restrict__ in,
    u16* __restrict__ out, int n4) {
  int i = blockIdx.x * 256 + threadIdx.x;
  if (i >= n4) return;
  float4 f = in[i];
  u16 o[4] = {f2bf(f.x), f2bf(f.y), f2bf(f.z), f2bf(f.w)};
  *(uint2*)&out[i * 4] = *(uint2*)o;
}

// ---------------- mask dtype detection + mask bias build ----------------
__global__ void detect_mask_dtype(const unsigned char* __restrict__ m, int* __restrict__ flag) {
  int i = blockIdx.x * 256 + threadIdx.x;  // scan first 8192 bytes
  if (i < 8192 && (i & 3) && m[i]) atomicOr(flag, 1);
}

// additive bias: 0 if attendable, -1e38 if masked/padding. index [b][MPAD]
__global__ void build_maskpad(const void* __restrict__ mask, const int* __restrict__ flag,
    float* __restrict__ mp) {
  int i = blockIdx.x * 256 + threadIdx.x;
  if (i >= 2 * MPAD) return;
  int b = i / MPAD, p = i - b * MPAD;
  float v;
  if (p == 0) v = 0.f;
  else if (p <= 4096) {
    int j = b * 4096 + (p - 1);
    int on = (*flag) ? (((const unsigned char*)mask)[j] != 0)
                     : (((const int*)mask)[j] != 0);
    v = on ? 0.f : -1e38f;
  } else v = -1e38f;
  mp[i] = v;
}

// ---------------- KVt: per (bh,kt) 8192-u16 tile: K-frags [0,4096) V-frags [4096,8192)
// K element (kl,d):  chunk = (((d>>4)*2 + ((d>>3)&1))*2 + (kl>>5))*32 + (kl&31), pos d&7
// V element (kl,d):  chunk = (((kl>>4)*2 + ((kl>>3)&1))*2 + (d>>5))*32 + (d&31), pos kl&7
__global__ __launch_bounds__(256) void fill_extras(const float* __restrict__ nullkv,
    u16* __restrict__ KVt) {
  int bh = blockIdx.x, tid = threadIdx.x;
  // zero tile kt=64 entirely (16 KB)
  size_t tb64 = ((size_t)bh * 65 + 64) * 8192;
  uint4 z = make_uint4(0, 0, 0, 0);
  for (int i = tid; i < 1024; i += 256)
    *(uint4*)&KVt[tb64 + (size_t)i * 8] = z;
  // null row kk=0 (tile 0, kl=0)
  size_t tb0 = (size_t)bh * 65 * 8192;
  if (tid < 64) {
    int d = tid;
    KVt[tb0 + (size_t)(d >> 3) * 512 + (d & 7)] = f2bf(nullkv[d] * QKS);
    KVt[tb0 + 4096 + (size_t)d * 8] = f2bf(nullkv[64 + d]);
  }
}

// ---------------- bf16 MFMA GEMM: C[M x N] = A[M x 512] * Bt[N x 512]^T -------------
// mode 0: out bf16 row-major [M][512]   (q projection, QKS folded in Bt)
// mode 1: scatter to KVt frag-layout (K scaled by QKS)
// mode 2: out fp32 row-major [M][512]
// staging via global_load_lds width=16 (no VGPR round-trip)
__global__ __launch_bounds__(256) void gemm_bf16(const u16* __restrict__ A,
    const u16* __restrict__ Bt, u16* __restrict__ outb, float* __restrict__ outf,
    u16* __restrict__ KVt, int Ncols, int mode) {
  __shared__ __attribute__((aligned(16))) u16 As[64 * 32];
  __shared__ __attribute__((aligned(16))) u16 Bs[64 * 32];
  int tiles_n = Ncols >> 6;
  int n0 = (blockIdx.x % tiles_n) * 64;
  int m0 = (blockIdx.x / tiles_n) * 64;
  int tid = threadIdx.x;
  int lane = tid & 63, w = tid >> 6, quad = lane >> 4, l15 = lane & 15;
  int arow = tid >> 2, acg = (tid & 3) * 8;
  v4f32 acc[4];
#pragma unroll
  for (int t = 0; t < 4; t++) acc[t] = (v4f32){0.f, 0.f, 0.f, 0.f};

  for (int k0 = 0; k0 < 512; k0 += 32) {
    __syncthreads();
    __builtin_amdgcn_global_load_lds((const u32*)&A[(size_t)(m0 + arow) * 512 + k0 + acg],
                                     (u32*)&As[tid * 8], 16, 0, 0);
    __builtin_amdgcn_global_load_lds((const u32*)&Bt[(size_t)(n0 + arow) * 512 + k0 + acg],
                                     (u32*)&Bs[tid * 8], 16, 0, 0);
    __syncthreads();
    v8bf16 af = *(const v8bf16*)&As[(w * 16 + l15) * 32 + quad * 8];
#pragma unroll
    for (int t = 0; t < 4; t++) {
      v8bf16 bf = *(const v8bf16*)&Bs[(t * 16 + l15) * 32 + quad * 8];
      acc[t] = __builtin_amdgcn_mfma_f32_16x16x32_bf16(af, bf, acc[t], 0, 0, 0);
    }
  }
  int rbase = m0 + w * 16 + quad * 4;
#pragma unroll
  for (int t = 0; t < 4; t++) {
    int col = n0 + t * 16 + l15;
#pragma unroll
    for (int r = 0; r < 4; r++) {
      float v = acc[t][r];
      int row = rbase + r;
      if (mode == 0) {
        outb[(size_t)row * 512 + col] = f2bf(v);
      } else if (mode == 2) {
        outf[(size_t)row * 512 + col] = v;
      } else {
        int b2 = row >> 12, mr = row & 4095;
        int kk = mr + 1, kt = kk >> 6, kl = kk & 63;
        int kvsel = col >> 9, hh = (col >> 6) & 7, d = col & 63;
        size_t tb = ((size_t)(b2 * 8 + hh) * 65 + kt) * 8192;
        if (kvsel == 0) {
          int chunk = (((d >> 4) * 2 + ((d >> 3) & 1)) * 2 + (kl >> 5)) * 32 + (kl & 31);
          KVt[tb + (size_t)chunk * 8 + (d & 7)] = f2bf(v * QKS);
        } else {
          int chunk = (((kl >> 4) * 2 + ((kl >> 3) & 1)) * 2 + (d >> 5)) * 32 + (d & 31);
          KVt[tb + 4096 + (size_t)chunk * 8 + (kl & 7)] = f2bf(v);
        }
      }
    }
  }
}

// ---------------- flash attention v7: split-K S=4, packed reg transform ----------
// grid: 2048 blocks of 256 thr (4 waves share one staged KV tile, single buffer).
// bid&31 = qt (128 q rows / block, 32 per wave); bid>>5 = bh*4 + s_p.
// ~96 total regs/thread -> 5 blocks/CU co-resident (grid now supplies them).
__global__ __launch_bounds__(256, 4) void attn_kernel(const u16* __restrict__ q,
    const u16* __restrict__ KVt, const float* __restrict__ maskbias,
    u32* __restrict__ Opart, float* __restrict__ lbuf) {
  __shared__ __attribute__((aligned(16))) u16 lds[8192];
  int bid = blockIdx.x;
  int qt = bid & 31, bhs = bid >> 5;
  int s_p = bhs & 3, bh = bhs >> 2;
  int b = bh >> 3, hh = bh & 7;
  int tid = threadIdx.x, lane = tid & 63, w = tid >> 6;
  int m31 = lane & 31, h = (lane >> 5) & 1;
  int grp = (bh * 32 + qt) * 4 + w;

  // Q B-frags: lane col = q0 + m31, k = ks*16 + h*8 (+0..7)
  int q0 = qt * 128 + w * 32;
  const u16* qp = q + (size_t)(b * 4096 + q0 + m31) * 512 + hh * 64 + h * 8;
  v8bf16 qf[4];
#pragma unroll
  for (int ks = 0; ks < 4; ks++) qf[ks] = *(const v8bf16*)&qp[ks * 16];

  v16f32 acc[2];
#pragma unroll
  for (int db = 0; db < 2; db++)
#pragma unroll
    for (int i = 0; i < 16; i++) acc[db][i] = 0.f;
  float l_st = 0.f;

  const u16* kvg = KVt + (size_t)bh * 65 * 8192;
  const float* mg = maskbias + b * MPAD;
  // 65 tiles split 17/16/16/16
  int kt0 = s_p * 16 + (s_p != 0 ? 1 : 0);
  int ktn = (s_p == 0) ? 17 : 16;

  for (int it = 0; it < ktn; ++it) {
    int kt = kt0 + it;
    __syncthreads();
    {
      // 16 KB staged by 4 waves
      const u16* gsrc = kvg + (size_t)kt * 8192 + (size_t)w * 512 + lane * 8;
#pragma unroll
      for (int i = 0; i < 4; i++) {
        __builtin_amdgcn_global_load_lds((const u32*)(gsrc + (size_t)i * 2048),
                                         (u32*)&lds[(i * 4 + w) * 512], 16, 0, 0);
      }
    }
    __syncthreads();

    // S^T = K * Q^T with mask bias as accumulator INIT
    // C layout: col q = m31, row key_local = (reg&3) + 8*(reg>>2) + 4h (+32*kc)
    v16f32 s[2];
#pragma unroll
    for (int kc = 0; kc < 2; kc++) {
#pragma unroll
      for (int gg = 0; gg < 4; gg++) {
        float4 bias = *(const float4*)&mg[kt * 64 + kc * 32 + gg * 8 + h * 4];
        s[kc][gg * 4 + 0] = bias.x;
        s[kc][gg * 4 + 1] = bias.y;
        s[kc][gg * 4 + 2] = bias.z;
        s[kc][gg * 4 + 3] = bias.w;
      }
#pragma unroll
      for (int ks = 0; ks < 4; ks++) {
        v8bf16 kf = *(const v8bf16*)&lds[(((ks * 2 + h) * 2 + kc) * 32 + m31) * 8];
        s[kc] = __builtin_amdgcn_mfma_f32_32x32x16_bf16(kf, qf[ks], s[kc], 0, 0, 0);
      }
    }

    // p = exp2(s) directly (raw v_exp_f32; masked s ~ -1e38 -> 0)
    float rsum = 0.f;
#pragma unroll
    for (int kc = 0; kc < 2; kc++)
#pragma unroll
      for (int i = 0; i < 16; i++) {
        float pv = __builtin_amdgcn_exp2f(s[kc][i]);
        s[kc][i] = pv;
        rsum += pv;
      }
    rsum += __shfl_xor(rsum, 32);
    l_st += rsum;

    // P C-layout -> B-frags: pack to bf16 pairs FIRST, then 8 u32 exchanges.
    // own lo = keys s16*16+4h+{0..3}, own hi = +8; frag jb=kc*2+s16 needs
    // keys jb*16 + h*8 + {0..7}.
    v8bf16 pf[4];
#pragma unroll
    for (int kc = 0; kc < 2; kc++)
#pragma unroll
      for (int s16 = 0; s16 < 2; s16++) {
        u32 plo0 = pkbf(s[kc][s16 * 8 + 0], s[kc][s16 * 8 + 1]);
        u32 plo1 = pkbf(s[kc][s16 * 8 + 2], s[kc][s16 * 8 + 3]);
        u32 phi0 = pkbf(s[kc][s16 * 8 + 4], s[kc][s16 * 8 + 5]);
        u32 phi1 = pkbf(s[kc][s16 * 8 + 6], s[kc][s16 * 8 + 7]);
        u32 snd0 = h ? plo0 : phi0;
        u32 snd1 = h ? plo1 : phi1;
        u32 rcv0 = (u32)__shfl_xor((int)snd0, 32);
        u32 rcv1 = (u32)__shfl_xor((int)snd1, 32);
        union { u32 u[4]; v8bf16 v; } pu;
        pu.u[0] = h ? rcv0 : plo0;
        pu.u[1] = h ? rcv1 : plo1;
        pu.u[2] = h ? phi0 : rcv0;
        pu.u[3] = h ? phi1 : rcv1;
        pf[kc * 2 + s16] = pu.v;
      }

    // O^T += V^T * P^T : A = V-frags (lane row d = db*32+m31)
#pragma unroll
    for (int jb = 0; jb < 4; jb++)
#pragma unroll
      for (int db = 0; db < 2; db++) {
        v8bf16 vf = *(const v8bf16*)&lds[4096 + (((jb * 2 + h) * 2 + db) * 32 + m31) * 8];
        acc[db] = __builtin_amdgcn_mfma_f32_32x32x16_bf16(vf, pf[jb], acc[db], 0, 0, 0);
      }
  }

  // epilogue: dump raw accumulator (bf16-packed) + l
  size_t ob = (size_t)(s_p * NGRP + grp) * 16 * 64;
#pragma unroll
  for (int db = 0; db < 2; db++)
#pragma unroll
    for (int rp = 0; rp < 8; rp++)
      Opart[ob + (size_t)(db * 8 + rp) * 64 + lane] = pkbf(acc[db][2 * rp], acc[db][2 * rp + 1]);
  if (h == 0)
    lbuf[(size_t)(s_p * NGRP + grp) * 32 + m31] = l_st;
}

// ---------------- combine 4 partials -> attnO (bf16 [row][512]) ----------------
__global__ __launch_bounds__(256) void attn_combine(const u32* __restrict__ Opart,
    const float* __restrict__ lbuf, u16* __restrict__ attnO) {
  __shared__ __attribute__((aligned(16))) u16 tl[4][2176];
  int tid = threadIdx.x, lane = tid & 63, w4 = tid >> 6;
  int m31 = lane & 31, h = (lane >> 5) & 1;
  int grp = blockIdx.x * 4 + w4;
  int wv = grp & 3, qt = (grp >> 2) & 31, bh = grp >> 7;
  int b = bh >> 3, hh = bh & 7;

  float lsum = 0.f;
#pragma unroll
  for (int sp = 0; sp < NSPLIT; sp++)
    lsum += lbuf[(size_t)(sp * NGRP + grp) * 32 + m31];
  float inv = 1.f / lsum;

#pragma unroll
  for (int db = 0; db < 2; db++)
#pragma unroll
    for (int rp = 0; rp < 8; rp++) {
      float fe = 0.f, fo = 0.f;
#pragma unroll
      for (int sp = 0; sp < NSPLIT; sp++) {
        u32 a = Opart[((size_t)(sp * NGRP + grp) * 16 + db * 8 + rp) * 64 + lane];
        fe += asf(a << 16);
        fo += asf(a & 0xFFFF0000u);
      }
      fe *= inv; fo *= inv;
      int reg = 2 * rp;
      int d0 = (reg & 3) + 8 * (reg >> 2) + 4 * h + 32 * db;
      *(u32*)&tl[w4][m31 * 68 + d0] = pkbf(fe, fo);
    }
  __builtin_amdgcn_s_waitcnt(0);  // wave-private LDS round-trip
  int q0 = qt * 128 + wv * 32;
#pragma unroll
  for (int t2 = 0; t2 < 4; t2++) {
    int row = t2 * 8 + (lane >> 3), ch = lane & 7;
    uint4 val = *(uint4*)&tl[w4][row * 68 + ch * 8];
    *(uint4*)&attnO[(size_t)(b * 4096 + q0 + row) * 512 + hh * 64 + ch * 8] = val;
  }
}

// =======================================================================
extern "C" void kernel_launch(void* const* d_in, const int* in_sizes, int n_in,
                              void* d_out, int out_size, void* d_ws, size_t ws_size,
                              hipStream_t stream) {
  const float* x       = (const float*)d_in[0];
  const float* context = (const float*)d_in[1];
  const void*  mask    = d_in[2];
  const float* g_x     = (const float*)d_in[3];
  const float* null_kv = (const float*)d_in[4];
  const float* Wq      = (const float*)d_in[5];
  const float* Wkv     = (const float*)d_in[6];
  const float* Wo      = (const float*)d_in[7];
  const float* g_out   = (const float*)d_in[8];

  char* w = (char*)d_ws;
  size_t off = 0;
  auto alloc = [&](size_t bytes) { size_t o = off; off = (off + bytes + 255) & ~(size_t)255; return o; };

  u16* WqT    = (u16*)(w + alloc((size_t)512 * 512 * 2));
  u16* WkvT   = (u16*)(w + alloc((size_t)1024 * 512 * 2));
  u16* WoT    = (u16*)(w + alloc((size_t)512 * 512 * 2));
  float* mp   = (float*)(w + alloc((size_t)2 * MPAD * 4));
  int* flag   = (int*)(w + alloc(256));
  u16* KVt    = (u16*)(w + alloc((size_t)16 * 65 * 8192 * 2));
  u16* qb     = (u16*)(w + alloc((size_t)8192 * 512 * 2));
  u16* aO     = (u16*)(w + alloc((size_t)8192 * 512 * 2));
  size_t xn_off = alloc((size_t)8192 * 512 * 2);   // 8 MB
  size_t cb_off = alloc((size_t)8192 * 512 * 2);   // 8 MB (contiguous with xn)
  size_t ext_off = alloc((size_t)16 * 1024 * 1024); // 16 MB (contiguous with cb)
  float* lbb  = (float*)(w + alloc((size_t)NSPLIT * NGRP * 32 * 4));
  u16* xn   = (u16*)(w + xn_off);
  u16* cb   = (u16*)(w + cb_off);
  (void)ext_off;
  // Opart (4*2048*16*64 u32 = 32 MB) spans xn+cb+ext (all dead after proj GEMMs)
  u32* Opart = (u32*)(w + xn_off);
  float* OP  = (float*)(w + xn_off);  // fp32 16 MB, used after combine (Opart dead)

  hipMemsetAsync(flag, 0, 4, stream);
  detect_mask_dtype<<<32, 256, 0, stream>>>((const unsigned char*)mask, flag);
  build_maskpad<<<(2 * MPAD + 255) / 256, 256, 0, stream>>>(mask, flag, mp);

  transpose_cast3<<<1024, 256, 0, stream>>>(Wq, Wkv, Wo, WqT, WkvT, WoT);

  ln_to_bf16<<<2048, 256, 0, stream>>>(x, g_x, xn);
  cast_f32_bf16<<<4096, 256, 0, stream>>>((const float4*)context, cb, 8192 * 512 / 4);
  fill_extras<<<16, 256, 0, stream>>>(null_kv, KVt);

  // q = ln(x) @ Wq * QKS   -> bf16 [8192][512]
  gemm_bf16<<<(8192 / 64) * (512 / 64), 256, 0, stream>>>(xn, WqT, qb, nullptr, nullptr, 512, 0);
  // kv = ctx @ Wkv -> scatter into KVt frag-layout (K x QKS)
  gemm_bf16<<<(8192 / 64) * (1024 / 64), 256, 0, stream>>>(cb, WkvT, nullptr, nullptr, KVt, 1024, 1);

  // split-K flash attention (S=4) + combine
  attn_kernel<<<2048, 256, 0, stream>>>(qb, KVt, mp, Opart, lbb);
  attn_combine<<<NGRP / 4, 256, 0, stream>>>(Opart, lbb, aO);

  // out = attnO @ Wo -> fp32
  gemm_bf16<<<(8192 / 64) * (512 / 64), 256, 0, stream>>>(aO, WoT, nullptr, OP, nullptr, 512, 2);
  ln_to_f32<<<2048, 256, 0, stream>>>(OP, g_out, (float*)d_out);
}

// Round 8
// 272.421 us; speedup vs baseline: 1.0761x; 1.0627x over previous
//
#include <hip/hip_runtime.h>
#include <cfloat>

typedef unsigned short u16;
typedef unsigned int u32;
typedef __bf16 v8bf16 __attribute__((ext_vector_type(8)));
typedef float v4f32 __attribute__((ext_vector_type(4)));
typedef float v16f32 __attribute__((ext_vector_type(16)));

#define MPAD 4224            // 4097 keys padded to 66*64
// sqrt(1/8) * sqrt(log2(e)) : folds head-scale AND base-2 softmax into q and k
#define QKS 0.42466090f
#define GRPS 1024            // waves per split: (16 bh) * (16 qt) * (4 w)

__device__ __forceinline__ u16 f2bf(float f) {
  union { float f; u32 u; } v; v.f = f;
  u32 u = v.u;
  u32 r = (u + 0x7FFFu + ((u >> 16) & 1u)) >> 16;
  return (u16)r;
}

// pack two f32 -> one u32 holding (bf16(hi)<<16)|bf16(lo), truncating
__device__ __forceinline__ u32 pkbf(float lo, float hi) {
  union { float f; u32 u; } a, c;
  a.f = lo; c.f = hi;
  return __builtin_amdgcn_perm(c.u, a.u, 0x07060302);
}

__device__ __forceinline__ float asf(u32 u) {
  union { u32 u; float f; } v; v.u = u; return v.f;
}

// ---------------- prep: fused transpose of Wq/Wkv/Wo fp32 [K][N] -> bf16 [N][K] ----
__global__ __launch_bounds__(256) void transpose_cast3(const float* __restrict__ Wq,
    const float* __restrict__ Wkv, const float* __restrict__ Wo,
    u16* __restrict__ WqT, u16* __restrict__ WkvT, u16* __restrict__ WoT) {
  __shared__ float tile[32][33];
  int bb = blockIdx.x;
  const float* in; u16* out; int N; float scale; int base;
  if (bb < 256)      { in = Wq;  out = WqT;  N = 512;  scale = QKS; base = bb; }
  else if (bb < 768) { in = Wkv; out = WkvT; N = 1024; scale = 1.f; base = bb - 256; }
  else               { in = Wo;  out = WoT;  N = 512;  scale = 1.f; base = bb - 768; }
  const int K = 512;
  int ntiles = N >> 5;
  int bx = base % ntiles, by = base / ntiles;
  int n0 = bx * 32, k0 = by * 32;
  int c = threadIdx.x & 31, r8 = threadIdx.x >> 5;
#pragma unroll
  for (int i = 0; i < 4; i++) {
    int r = r8 + i * 8;
    tile[r][c] = in[(size_t)(k0 + r) * N + n0 + c];
  }
  __syncthreads();
#pragma unroll
  for (int i = 0; i < 4; i++) {
    int r = r8 + i * 8;
    out[(size_t)(n0 + r) * K + k0 + c] = f2bf(tile[c][r] * scale);
  }
}

// ---------------- layernorm fp32 row(512) -> bf16 ----------------
__global__ __launch_bounds__(256) void ln_to_bf16(const float* __restrict__ in,
    const float* __restrict__ g, u16* __restrict__ out) {
  int lane = threadIdx.x & 63, w = threadIdx.x >> 6;
  int row = blockIdx.x * 4 + w;
  const float* p = in + (size_t)row * 512 + lane * 8;
  float4 f0 = *(const float4*)p;
  float4 f1 = *(const float4*)(p + 4);
  float v[8] = {f0.x, f0.y, f0.z, f0.w, f1.x, f1.y, f1.z, f1.w};
  float sum = 0.f, sq = 0.f;
#pragma unroll
  for (int i = 0; i < 8; i++) { sum += v[i]; sq += v[i] * v[i]; }
#pragma unroll
  for (int m = 1; m < 64; m <<= 1) { sum += __shfl_xor(sum, m); sq += __shfl_xor(sq, m); }
  float mean = sum * (1.f / 512.f);
  float var = sq * (1.f / 512.f) - mean * mean;
  float rstd = rsqrtf(var + 1e-5f);
  const float* gp = g + lane * 8;
  u16 o[8];
#pragma unroll
  for (int i = 0; i < 8; i++) o[i] = f2bf((v[i] - mean) * rstd * gp[i]);
  *(uint4*)&out[(size_t)row * 512 + lane * 8] = *(uint4*)o;
}

// ---------------- layernorm fp32 row(512) -> fp32 (final) ----------------
__global__ __launch_bounds__(256) void ln_to_f32(const float* __restrict__ in,
    const float* __restrict__ g, float* __restrict__ out) {
  int lane = threadIdx.x & 63, w = threadIdx.x >> 6;
  int row = blockIdx.x * 4 + w;
  const float* p = in + (size_t)row * 512 + lane * 8;
  float4 f0 = *(const float4*)p;
  float4 f1 = *(const float4*)(p + 4);
  float v[8] = {f0.x, f0.y, f0.z, f0.w, f1.x, f1.y, f1.z, f1.w};
  float sum = 0.f, sq = 0.f;
#pragma unroll
  for (int i = 0; i < 8; i++) { sum += v[i]; sq += v[i] * v[i]; }
#pragma unroll
  for (int m = 1; m < 64; m <<= 1) { sum += __shfl_xor(sum, m); sq += __shfl_xor(sq, m); }
  float mean = sum * (1.f / 512.f);
  float var = sq * (1.f / 512.f) - mean * mean;
  float rstd = rsqrtf(var + 1e-5f);
  const float* gp = g + lane * 8;
  float o[8];
#pragma unroll
  for (int i = 0; i < 8; i++) o[i] = (v[i] - mean) * rstd * gp[i];
  float* q = out + (size_t)row * 512 + lane * 8;
  *(float4*)q = make_float4(o[0], o[1], o[2], o[3]);
  *(float4*)(q + 4) = make_float4(o[4], o[5], o[6], o[7]);
}

// ---------------- cast fp32 -> bf16 ----------------
__global__ __launch_bounds__(256) void cast_f32_bf16(const float4* __restrict__ in,
    u16* __restrict__ out, int n4) {
  int i = blockIdx.x * 256 + threadIdx.x;
  if (i >= n4) return;
  float4 f = in[i];
  u16 o[4] = {f2bf(f.x), f2bf(f.y), f2bf(f.z), f2bf(f.w)};
  *(uint2*)&out[i * 4] = *(uint2*)o;
}

// ---------------- mask dtype detection + mask bias build ----------------
__global__ void detect_mask_dtype(const unsigned char* __restrict__ m, int* __restrict__ flag) {
  int i = blockIdx.x * 256 + threadIdx.x;  // scan first 8192 bytes
  if (i < 8192 && (i & 3) && m[i]) atomicOr(flag, 1);
}

// additive bias: 0 if attendable, -1e38 if masked/padding. index [b][MPAD]
__global__ void build_maskpad(const void* __restrict__ mask, const int* __restrict__ flag,
    float* __restrict__ mp) {
  int i = blockIdx.x * 256 + threadIdx.x;
  if (i >= 2 * MPAD) return;
  int b = i / MPAD, p = i - b * MPAD;
  float v;
  if (p == 0) v = 0.f;
  else if (p <= 4096) {
    int j = b * 4096 + (p - 1);
    int on = (*flag) ? (((const unsigned char*)mask)[j] != 0)
                     : (((const int*)mask)[j] != 0);
    v = on ? 0.f : -1e38f;
  } else v = -1e38f;
  mp[i] = v;
}

// ---------------- KVt: per (bh,kt) 8192-u16 tile (66 tiles/bh):
// K-frags [0,4096): element (kl,d): u16 idx = (d>>3)*128*... chunk form:
//   chunk = (((d>>4)*2 + ((d>>3)&1))*2 + (kl>>5))*32 + (kl&31), pos d&7
// V-frags [4096,8192): chunk = (((kl>>4)*2 + ((kl>>3)&1))*2 + (d>>5))*32 + (d&31), pos kl&7
__global__ __launch_bounds__(256) void fill_extras(const float* __restrict__ nullkv,
    u16* __restrict__ KVt) {
  int bh = blockIdx.x, tid = threadIdx.x;
  // zero tiles 64 and 65 entirely (32 KB)
  size_t tb64 = ((size_t)bh * 66 + 64) * 8192;
  uint4 z = make_uint4(0, 0, 0, 0);
  for (int i = tid; i < 2048; i += 256)
    *(uint4*)&KVt[tb64 + (size_t)i * 8] = z;
  // null row kk=0 (tile 0, kl=0)
  size_t tb0 = (size_t)bh * 66 * 8192;
  if (tid < 64) {
    int d = tid;
    KVt[tb0 + (size_t)(d >> 3) * 512 + (d & 7)] = f2bf(nullkv[d] * QKS);
    KVt[tb0 + 4096 + (size_t)d * 8] = f2bf(nullkv[64 + d]);
  }
}

// ---------------- bf16 MFMA GEMM: C[M x N] = A[M x 512] * Bt[N x 512]^T -------------
// 128x64 tile, 256 thr (4 waves, each 32 rows x 64 cols)
// mode 0: out bf16 row-major [M][512]; mode 1: scatter to KVt frag-layout;
// mode 2: out fp32 row-major [M][512]
__global__ __launch_bounds__(256) void gemm_bf16(const u16* __restrict__ A,
    const u16* __restrict__ Bt, u16* __restrict__ outb, float* __restrict__ outf,
    u16* __restrict__ KVt, int Ncols, int mode) {
  __shared__ __attribute__((aligned(16))) u16 As[128 * 32];
  __shared__ __attribute__((aligned(16))) u16 Bs[64 * 32];
  int tiles_n = Ncols >> 6;
  int n0 = (blockIdx.x % tiles_n) * 64;
  int m0 = (blockIdx.x / tiles_n) * 128;
  int tid = threadIdx.x;
  int lane = tid & 63, w = tid >> 6, quad = lane >> 4, l15 = lane & 15;
  int srow = tid >> 2, scol = (tid & 3) * 8;
  v4f32 acc[2][4];
#pragma unroll
  for (int i = 0; i < 2; i++)
#pragma unroll
    for (int j = 0; j < 4; j++) acc[i][j] = (v4f32){0.f, 0.f, 0.f, 0.f};

  for (int k0 = 0; k0 < 512; k0 += 32) {
    __syncthreads();
    __builtin_amdgcn_global_load_lds((const u32*)&A[(size_t)(m0 + srow) * 512 + k0 + scol],
                                     (u32*)&As[tid * 8], 16, 0, 0);
    __builtin_amdgcn_global_load_lds((const u32*)&A[(size_t)(m0 + 64 + srow) * 512 + k0 + scol],
                                     (u32*)&As[64 * 32 + tid * 8], 16, 0, 0);
    __builtin_amdgcn_global_load_lds((const u32*)&Bt[(size_t)(n0 + srow) * 512 + k0 + scol],
                                     (u32*)&Bs[tid * 8], 16, 0, 0);
    __syncthreads();
    v8bf16 af[2], bf[4];
#pragma unroll
    for (int i = 0; i < 2; i++)
      af[i] = *(const v8bf16*)&As[(w * 32 + i * 16 + l15) * 32 + quad * 8];
#pragma unroll
    for (int j = 0; j < 4; j++)
      bf[j] = *(const v8bf16*)&Bs[(j * 16 + l15) * 32 + quad * 8];
#pragma unroll
    for (int i = 0; i < 2; i++)
#pragma unroll
      for (int j = 0; j < 4; j++)
        acc[i][j] = __builtin_amdgcn_mfma_f32_16x16x32_bf16(af[i], bf[j], acc[i][j], 0, 0, 0);
  }
#pragma unroll
  for (int i = 0; i < 2; i++) {
    int rbase = m0 + w * 32 + i * 16 + quad * 4;
#pragma unroll
    for (int j = 0; j < 4; j++) {
      int col = n0 + j * 16 + l15;
#pragma unroll
      for (int r = 0; r < 4; r++) {
        float v = acc[i][j][r];
        int row = rbase + r;
        if (mode == 0) {
          outb[(size_t)row * 512 + col] = f2bf(v);
        } else if (mode == 2) {
          outf[(size_t)row * 512 + col] = v;
        } else {
          int b2 = row >> 12, mr = row & 4095;
          int kk = mr + 1, kt = kk >> 6, kl = kk & 63;
          int kvsel = col >> 9, hh = (col >> 6) & 7, d = col & 63;
          size_t tb = ((size_t)(b2 * 8 + hh) * 66 + kt) * 8192;
          if (kvsel == 0) {
            int chunk = (((d >> 4) * 2 + ((d >> 3) & 1)) * 2 + (kl >> 5)) * 32 + (kl & 31);
            KVt[tb + (size_t)chunk * 8 + (d & 7)] = f2bf(v * QKS);
          } else {
            int chunk = (((kl >> 4) * 2 + ((kl >> 3) & 1)) * 2 + (d >> 5)) * 32 + (d & 31);
            KVt[tb + 4096 + (size_t)chunk * 8 + (kl & 7)] = f2bf(v);
          }
        }
      }
    }
  }
}

// ---------------- flash attention v8: barrier-free, register-resident K/V ----------
// grid: 512 blocks x 256 thr; waves fully independent (NO __syncthreads in loop).
// bid&15 = qt (256 q rows/block); bid>>4 = bh*2 + s_p. Wave handles 64 q rows
// (2 groups of 32) x 33 K-tiles, loading K/V fragments straight from the
// frag-contiguous KVt into VGPRs (no LDS).  S=2 split-K; partials to Opart.
__global__ __launch_bounds__(256, 2) void attn_kernel(const u16* __restrict__ q,
    const u16* __restrict__ KVt, const float* __restrict__ maskbias,
    u32* __restrict__ Opart, float* __restrict__ lbuf) {
  int bid = blockIdx.x;
  int qt = bid & 15, bhs = bid >> 4;
  int s_p = bhs & 1, bh = bhs >> 1;
  int b = bh >> 3, hh = bh & 7;
  int tid = threadIdx.x, lane = tid & 63, w = tid >> 6;
  int m31 = lane & 31, h = (lane >> 5) & 1;
  int grp = (bh * 16 + qt) * 4 + w;
  int q0 = qt * 256 + w * 64;

  // Q B-frags for both 32-row groups: lane col = q0 + qg*32 + m31, k = ks*16+h*8
  v8bf16 qf[2][4];
#pragma unroll
  for (int qg = 0; qg < 2; qg++) {
    const u16* qp = q + (size_t)(b * 4096 + q0 + qg * 32 + m31) * 512 + hh * 64 + h * 8;
#pragma unroll
    for (int ks = 0; ks < 4; ks++) qf[qg][ks] = *(const v8bf16*)&qp[ks * 16];
  }

  v16f32 acc[2][2];
#pragma unroll
  for (int qg = 0; qg < 2; qg++)
#pragma unroll
    for (int db = 0; db < 2; db++)
#pragma unroll
      for (int i = 0; i < 16; i++) acc[qg][db][i] = 0.f;
  float l_st[2] = {0.f, 0.f};

  // lane-fixed base into KVt: + (h*64 + m31)*8 u16
  const u16* kvb = KVt + (size_t)bh * 66 * 8192 + (size_t)(h * 64 + m31) * 8;
  const float* mg = maskbias + b * MPAD;
  int kt0 = s_p * 33;

  for (int kt = kt0; kt < kt0 + 33; ++kt) {
    const u16* tb = kvb + (size_t)kt * 8192;
    // K frags: ks(4) x kc(2), each 16B: offset ks*1024 + kc*256 u16
    v8bf16 kf[4][2];
#pragma unroll
    for (int ks = 0; ks < 4; ks++)
#pragma unroll
      for (int kc = 0; kc < 2; kc++)
        kf[ks][kc] = *(const v8bf16*)&tb[ks * 1024 + kc * 256];
    // bias (C-init values), reused by both q-groups
    v16f32 bias_s[2];
#pragma unroll
    for (int kc = 0; kc < 2; kc++)
#pragma unroll
      for (int gg = 0; gg < 4; gg++) {
        float4 bv = *(const float4*)&mg[kt * 64 + kc * 32 + gg * 8 + h * 4];
        bias_s[kc][gg * 4 + 0] = bv.x;
        bias_s[kc][gg * 4 + 1] = bv.y;
        bias_s[kc][gg * 4 + 2] = bv.z;
        bias_s[kc][gg * 4 + 3] = bv.w;
      }

    v8bf16 pf[2][4];
    // ---- q-group 0: copy bias into s, QK, exp, pack
    {
      v16f32 s[2];
#pragma unroll
      for (int kc = 0; kc < 2; kc++) {
        s[kc] = bias_s[kc];
#pragma unroll
        for (int ks = 0; ks < 4; ks++)
          s[kc] = __builtin_amdgcn_mfma_f32_32x32x16_bf16(kf[ks][kc], qf[0][ks], s[kc], 0, 0, 0);
      }
      float rsum = 0.f;
#pragma unroll
      for (int kc = 0; kc < 2; kc++)
#pragma unroll
        for (int i = 0; i < 16; i++) {
          float pv = __builtin_amdgcn_exp2f(s[kc][i]);
          s[kc][i] = pv;
          rsum += pv;
        }
      rsum += __shfl_xor(rsum, 32);
      l_st[0] += rsum;
#pragma unroll
      for (int kc = 0; kc < 2; kc++)
#pragma unroll
        for (int s16 = 0; s16 < 2; s16++) {
          u32 plo0 = pkbf(s[kc][s16 * 8 + 0], s[kc][s16 * 8 + 1]);
          u32 plo1 = pkbf(s[kc][s16 * 8 + 2], s[kc][s16 * 8 + 3]);
          u32 phi0 = pkbf(s[kc][s16 * 8 + 4], s[kc][s16 * 8 + 5]);
          u32 phi1 = pkbf(s[kc][s16 * 8 + 6], s[kc][s16 * 8 + 7]);
          u32 snd0 = h ? plo0 : phi0;
          u32 snd1 = h ? plo1 : phi1;
          u32 rcv0 = (u32)__shfl_xor((int)snd0, 32);
          u32 rcv1 = (u32)__shfl_xor((int)snd1, 32);
          union { u32 u[4]; v8bf16 v; } pu;
          pu.u[0] = h ? rcv0 : plo0;
          pu.u[1] = h ? rcv1 : plo1;
          pu.u[2] = h ? phi0 : rcv0;
          pu.u[3] = h ? phi1 : rcv1;
          pf[0][kc * 2 + s16] = pu.v;
        }
    }
    // ---- q-group 1: accumulate INTO the bias registers (saves a copy + regs)
    {
#pragma unroll
      for (int kc = 0; kc < 2; kc++)
#pragma unroll
        for (int ks = 0; ks < 4; ks++)
          bias_s[kc] = __builtin_amdgcn_mfma_f32_32x32x16_bf16(kf[ks][kc], qf[1][ks], bias_s[kc], 0, 0, 0);
      float rsum = 0.f;
#pragma unroll
      for (int kc = 0; kc < 2; kc++)
#pragma unroll
        for (int i = 0; i < 16; i++) {
          float pv = __builtin_amdgcn_exp2f(bias_s[kc][i]);
          bias_s[kc][i] = pv;
          rsum += pv;
        }
      rsum += __shfl_xor(rsum, 32);
      l_st[1] += rsum;
#pragma unroll
      for (int kc = 0; kc < 2; kc++)
#pragma unroll
        for (int s16 = 0; s16 < 2; s16++) {
          u32 plo0 = pkbf(bias_s[kc][s16 * 8 + 0], bias_s[kc][s16 * 8 + 1]);
          u32 plo1 = pkbf(bias_s[kc][s16 * 8 + 2], bias_s[kc][s16 * 8 + 3]);
          u32 phi0 = pkbf(bias_s[kc][s16 * 8 + 4], bias_s[kc][s16 * 8 + 5]);
          u32 phi1 = pkbf(bias_s[kc][s16 * 8 + 6], bias_s[kc][s16 * 8 + 7]);
          u32 snd0 = h ? plo0 : phi0;
          u32 snd1 = h ? plo1 : phi1;
          u32 rcv0 = (u32)__shfl_xor((int)snd0, 32);
          u32 rcv1 = (u32)__shfl_xor((int)snd1, 32);
          union { u32 u[4]; v8bf16 v; } pu;
          pu.u[0] = h ? rcv0 : plo0;
          pu.u[1] = h ? rcv1 : plo1;
          pu.u[2] = h ? phi0 : rcv0;
          pu.u[3] = h ? phi1 : rcv1;
          pf[1][kc * 2 + s16] = pu.v;
        }
    }

    // V frags: jb(4) x db(2) at u16 offset 4096 + jb*1024 + db*256 (K regs now dead)
    v8bf16 vf[4][2];
#pragma unroll
    for (int jb = 0; jb < 4; jb++)
#pragma unroll
      for (int db = 0; db < 2; db++)
        vf[jb][db] = *(const v8bf16*)&tb[4096 + jb * 1024 + db * 256];

    // O^T += V^T * P^T for both q-groups
#pragma unroll
    for (int qg = 0; qg < 2; qg++)
#pragma unroll
      for (int jb = 0; jb < 4; jb++)
#pragma unroll
        for (int db = 0; db < 2; db++)
          acc[qg][db] = __builtin_amdgcn_mfma_f32_32x32x16_bf16(vf[jb][db], pf[qg][jb], acc[qg][db], 0, 0, 0);
  }

  // epilogue: dump raw accumulator (bf16-packed) + l
  size_t ob = (size_t)(s_p * GRPS + grp) * 2048;
#pragma unroll
  for (int qg = 0; qg < 2; qg++)
#pragma unroll
    for (int db = 0; db < 2; db++)
#pragma unroll
      for (int rp = 0; rp < 8; rp++)
        Opart[ob + qg * 1024 + (size_t)(db * 8 + rp) * 64 + lane] =
            pkbf(acc[qg][db][2 * rp], acc[qg][db][2 * rp + 1]);
  if (h == 0) {
    lbuf[(size_t)(s_p * GRPS + grp) * 64 + m31] = l_st[0];
    lbuf[(size_t)(s_p * GRPS + grp) * 64 + 32 + m31] = l_st[1];
  }
}

// ---------------- combine 2 partials -> attnO (bf16 [row][512]) ----------------
__global__ __launch_bounds__(256) void attn_combine(const u32* __restrict__ Opart,
    const float* __restrict__ lbuf, u16* __restrict__ attnO) {
  __shared__ __attribute__((aligned(16))) u16 tl[4][2176];
  int tid = threadIdx.x, lane = tid & 63, w4 = tid >> 6;
  int m31 = lane & 31, h = (lane >> 5) & 1;
  int gq = blockIdx.x * 4 + w4;        // 0..2047 = (grp, qg)
  int qg = gq & 1, grp = gq >> 1;
  int w = grp & 3, qt = (grp >> 2) & 15, bh = grp >> 6;
  int b = bh >> 3, hh = bh & 7;

  float l0 = lbuf[(size_t)grp * 64 + qg * 32 + m31];
  float l1 = lbuf[(size_t)(GRPS + grp) * 64 + qg * 32 + m31];
  float inv = 1.f / (l0 + l1);

#pragma unroll
  for (int db = 0; db < 2; db++)
#pragma unroll
    for (int rp = 0; rp < 8; rp++) {
      u32 a = Opart[(size_t)grp * 2048 + qg * 1024 + (db * 8 + rp) * 64 + lane];
      u32 c = Opart[(size_t)(GRPS + grp) * 2048 + qg * 1024 + (db * 8 + rp) * 64 + lane];
      float fe = (asf(a << 16) + asf(c << 16)) * inv;
      float fo = (asf(a & 0xFFFF0000u) + asf(c & 0xFFFF0000u)) * inv;
      int reg = 2 * rp;
      int d0 = (reg & 3) + 8 * (reg >> 2) + 4 * h + 32 * db;
      *(u32*)&tl[w4][m31 * 68 + d0] = pkbf(fe, fo);
    }
  __builtin_amdgcn_s_waitcnt(0);  // wave-private LDS round-trip
  int q0 = qt * 256 + w * 64 + qg * 32;
#pragma unroll
  for (int t2 = 0; t2 < 4; t2++) {
    int row = t2 * 8 + (lane >> 3), ch = lane & 7;
    uint4 val = *(uint4*)&tl[w4][row * 68 + ch * 8];
    *(uint4*)&attnO[(size_t)(b * 4096 + q0 + row) * 512 + hh * 64 + ch * 8] = val;
  }
}

// =======================================================================
extern "C" void kernel_launch(void* const* d_in, const int* in_sizes, int n_in,
                              void* d_out, int out_size, void* d_ws, size_t ws_size,
                              hipStream_t stream) {
  const float* x       = (const float*)d_in[0];
  const float* context = (const float*)d_in[1];
  const void*  mask    = d_in[2];
  const float* g_x     = (const float*)d_in[3];
  const float* null_kv = (const float*)d_in[4];
  const float* Wq      = (const float*)d_in[5];
  const float* Wkv     = (const float*)d_in[6];
  const float* Wo      = (const float*)d_in[7];
  const float* g_out   = (const float*)d_in[8];

  char* w = (char*)d_ws;
  size_t off = 0;
  auto alloc = [&](size_t bytes) { size_t o = off; off = (off + bytes + 255) & ~(size_t)255; return o; };

  u16* WqT    = (u16*)(w + alloc((size_t)512 * 512 * 2));
  u16* WkvT   = (u16*)(w + alloc((size_t)1024 * 512 * 2));
  u16* WoT    = (u16*)(w + alloc((size_t)512 * 512 * 2));
  float* mp   = (float*)(w + alloc((size_t)2 * MPAD * 4));
  int* flag   = (int*)(w + alloc(256));
  u16* KVt    = (u16*)(w + alloc((size_t)16 * 66 * 8192 * 2));
  u16* qb     = (u16*)(w + alloc((size_t)8192 * 512 * 2));
  u16* aO     = (u16*)(w + alloc((size_t)8192 * 512 * 2));
  size_t xn_off = alloc((size_t)8192 * 512 * 2);   // 8 MB
  size_t cb_off = alloc((size_t)8192 * 512 * 2);   // 8 MB (contiguous with xn)
  float* lbb  = (float*)(w + alloc((size_t)2 * GRPS * 64 * 4));
  u16* xn   = (u16*)(w + xn_off);
  u16* cb   = (u16*)(w + cb_off);
  // Opart (2*1024*2048 u32 = 16.78 MB) aliases xn+cb exactly (dead after proj GEMMs)
  u32* Opart = (u32*)(w + xn_off);
  float* OP  = (float*)(w + xn_off);  // fp32 16 MB, used after combine (Opart dead)

  hipMemsetAsync(flag, 0, 4, stream);
  detect_mask_dtype<<<32, 256, 0, stream>>>((const unsigned char*)mask, flag);
  build_maskpad<<<(2 * MPAD + 255) / 256, 256, 0, stream>>>(mask, flag, mp);

  transpose_cast3<<<1024, 256, 0, stream>>>(Wq, Wkv, Wo, WqT, WkvT, WoT);

  ln_to_bf16<<<2048, 256, 0, stream>>>(x, g_x, xn);
  cast_f32_bf16<<<4096, 256, 0, stream>>>((const float4*)context, cb, 8192 * 512 / 4);
  fill_extras<<<16, 256, 0, stream>>>(null_kv, KVt);

  // q = ln(x) @ Wq * QKS   -> bf16 [8192][512]
  gemm_bf16<<<(8192 / 128) * (512 / 64), 256, 0, stream>>>(xn, WqT, qb, nullptr, nullptr, 512, 0);
  // kv = ctx @ Wkv -> scatter into KVt frag-layout (K x QKS)
  gemm_bf16<<<(8192 / 128) * (1024 / 64), 256, 0, stream>>>(cb, WkvT, nullptr, nullptr, KVt, 1024, 1);

  // barrier-free split-K flash attention (S=2) + combine
  attn_kernel<<<512, 256, 0, stream>>>(qb, KVt, mp, Opart, lbb);
  attn_combine<<<512, 256, 0, stream>>>(Opart, lbb, aO);

  // out = attnO @ Wo -> fp32
  gemm_bf16<<<(8192 / 128) * (512 / 64), 256, 0, stream>>>(aO, WoT, nullptr, OP, nullptr, 512, 2);
  ln_to_f32<<<2048, 256, 0, stream>>>(OP, g_out, (float*)d_out);
}